// Round 5
// baseline (351.826 us; speedup 1.0000x reference)
//
#include <hip/hip_runtime.h>

// VQ-VAE quantization, round 5: round-4 f16 MFMA pipeline, hardened:
// no atomics, no memset, deterministic compaction, clamped indices.
// N=32768 rows (D=256), K=1024 codes.
// dist = ||e_k||^2 - 2 z.e_k  (||z||^2 dropped: argmin-invariant)
// Approx dot = f16(z).f16(e) in fp32 accum; rows with top-2 gap < TAU
// get exact fp32 re-check against the whole codebook.

#define N_ROWS 32768
#define K_CODES 1024
#define D_DIM 256
#define M_ELEMS 8388608   // N_ROWS * D_DIM

#define TM 128
#define TN 128
#define BK 64
#define TAU 0.25f
#define CAP 8192
#define RPB 8             // cleanup rows per block

typedef __attribute__((ext_vector_type(8))) _Float16 half8;
typedef __attribute__((ext_vector_type(4))) _Float16 half4;
typedef __attribute__((ext_vector_type(4))) float f32x4;
typedef __attribute__((ext_vector_type(4), aligned(4))) float f4u;

__device__ inline void async16(const void* g, void* l) {
    __builtin_amdgcn_global_load_lds(
        (const __attribute__((address_space(1))) unsigned int*)g,
        (__attribute__((address_space(3))) unsigned int*)l, 16, 0, 0);
}

// ---------------- fp32 -> f16 (RN) ----------------
__global__ void convert_f16_kernel(const float* __restrict__ src,
                                   _Float16* __restrict__ dst, int n4) {
    int stride = gridDim.x * blockDim.x;
    for (int i = blockIdx.x * blockDim.x + threadIdx.x; i < n4; i += stride) {
        float4 v = *(const float4*)(src + (size_t)i * 4);
        half4 h = {(_Float16)v.x, (_Float16)v.y, (_Float16)v.z, (_Float16)v.w};
        *(half4*)(dst + (size_t)i * 4) = h;
    }
}

// ---------------- codebook prep: f16 copy + fp32 transpose (1D grid) ----------------
__global__ void prep_codebook_kernel(const float* __restrict__ cbk,
                                     float* __restrict__ cbkT,
                                     _Float16* __restrict__ eh) {
    __shared__ float tile[32][33];
    int b  = blockIdx.x;              // 0..255
    int bk = b & 31;                  // code block
    int bd = b >> 5;                  // dim block (0..7)
    int r  = threadIdx.x >> 3;        // 0..31
    int c4 = (threadIdx.x & 7) * 4;   // 0,4,..,28
    int k = bk * 32 + r;
    int d = bd * 32 + c4;
    float4 v = *(const float4*)(cbk + (size_t)k * D_DIM + d);
    half4 h = {(_Float16)v.x, (_Float16)v.y, (_Float16)v.z, (_Float16)v.w};
    *(half4*)(eh + (size_t)k * D_DIM + d) = h;
    tile[r][c4 + 0] = v.x; tile[r][c4 + 1] = v.y;
    tile[r][c4 + 2] = v.z; tile[r][c4 + 3] = v.w;
    __syncthreads();
    float4 o = {tile[c4 + 0][r], tile[c4 + 1][r], tile[c4 + 2][r], tile[c4 + 3][r]};
    *(float4*)(cbkT + (size_t)(bd * 32 + r) * K_CODES + bk * 32 + c4) = o;
}

// ---------------- codebook norms (exact fp32) ----------------
__global__ void norms_kernel(const float* __restrict__ cbk, float* __restrict__ norms) {
    int wave = threadIdx.x >> 6;
    int lane = threadIdx.x & 63;
    int code = blockIdx.x * 4 + wave;       // grid = K/4 = 256
    const float4 v = *(const float4*)(cbk + (size_t)code * D_DIM + lane * 4);
    float s = v.x * v.x + v.y * v.y + v.z * v.z + v.w * v.w;
    #pragma unroll
    for (int off = 32; off; off >>= 1) s += __shfl_down(s, off);
    if (lane == 0) norms[code] = s;
}

// ---------------- main: f16 MFMA, global_load_lds, XOR-swizzled LDS ----------------
__global__ __launch_bounds__(256, 2) void vq_main_f16(
    const _Float16* __restrict__ zh, const _Float16* __restrict__ eh,
    const float* __restrict__ norms,
    float* __restrict__ pval, int* __restrict__ pidx, float* __restrict__ pval2)
{
    __shared__ __align__(16) _Float16 Ah[TM * BK];
    __shared__ __align__(16) _Float16 Bh[TN * BK];

    const int tid  = threadIdx.x;
    const int bid  = blockIdx.x;            // grid = 256 * 8 = 2048
    const int cbl  = bid & 7;
    const int rb   = bid >> 3;
    const int rbase = rb * TM;
    const int cbase = cbl * TN;

    const int w    = tid >> 6;
    const int lane = tid & 63;
    const int quad = lane >> 4;
    const int ml   = lane & 15;
    const int wrow = (w >> 1) * 64;
    const int wcol = (w & 1) * 64;

    f32x4 acc[4][4];
    #pragma unroll
    for (int i = 0; i < 4; ++i)
        #pragma unroll
        for (int j = 0; j < 4; ++j)
            acc[i][j] = (f32x4){0.f, 0.f, 0.f, 0.f};

    for (int dc = 0; dc < D_DIM / BK; ++dc) {   // 4 iterations
        // LDS slot (row,seg) holds global k-chunk seg^(row&7): XOR swizzle on
        // the SOURCE address (global_load_lds dest must stay lane-linear).
        #pragma unroll
        for (int q = 0; q < 4; ++q) {
            int cc  = q * 256 + tid;        // 0..1023
            int row = cc >> 3;
            int seg = cc & 7;
            int sg  = seg ^ (row & 7);
            async16(zh + (size_t)(rbase + row) * D_DIM + dc * BK + sg * 8, &Ah[cc * 8]);
            async16(eh + (size_t)(cbase + row) * D_DIM + dc * BK + sg * 8, &Bh[cc * 8]);
        }
        __syncthreads();

        half8 a[4][2];
        #pragma unroll
        for (int i = 0; i < 4; ++i) {
            int r = wrow + i * 16 + ml;
            #pragma unroll
            for (int kc = 0; kc < 2; ++kc)
                a[i][kc] = *(const half8*)&Ah[r * BK + (((kc << 2) + quad) ^ (r & 7)) * 8];
        }
        #pragma unroll
        for (int j = 0; j < 4; ++j) {
            int c = wcol + j * 16 + ml;
            #pragma unroll
            for (int kc = 0; kc < 2; ++kc) {
                half8 b = *(const half8*)&Bh[c * BK + (((kc << 2) + quad) ^ (c & 7)) * 8];
                #pragma unroll
                for (int i = 0; i < 4; ++i)
                    acc[i][j] = __builtin_amdgcn_mfma_f32_16x16x32_f16(a[i][kc], b, acc[i][j], 0, 0, 0);
            }
        }
        __syncthreads();
    }

    // ------- per-row top-2 over this block's 128 codes -------
    float nrm[4];
    int   codej[4];
    #pragma unroll
    for (int j = 0; j < 4; ++j) {
        codej[j] = cbase + wcol + j * 16 + ml;
        nrm[j]   = norms[codej[j]];
    }

    float* rv1 = (float*)Ah;   // [128][2] overlays (loop ended on syncthreads)
    int*   rid = (int*)&Ah[TM * BK / 2];
    float* rv2 = (float*)Bh;

    #pragma unroll
    for (int i = 0; i < 4; ++i) {
        #pragma unroll
        for (int r = 0; r < 4; ++r) {
            float m1 = 3.4e38f, m2 = 3.4e38f;
            int   i1 = cbase;    // safe default (valid code) even if all dists NaN
            #pragma unroll
            for (int j = 0; j < 4; ++j) {
                float dist = nrm[j] - 2.f * acc[i][j][r];
                int code = codej[j];
                if (dist < m1 || (dist == m1 && code < i1)) { m2 = m1; m1 = dist; i1 = code; }
                else m2 = fminf(m2, dist);
            }
            #pragma unroll
            for (int off = 1; off < 16; off <<= 1) {
                float om1 = __shfl_xor(m1, off);
                int   oi1 = __shfl_xor(i1, off);
                float om2 = __shfl_xor(m2, off);
                if (om1 < m1 || (om1 == m1 && oi1 < i1)) { m2 = fminf(m1, om2); m1 = om1; i1 = oi1; }
                else m2 = fminf(m2, om1);
            }
            if (ml == 0) {
                int rl = wrow + i * 16 + quad * 4 + r;
                rv1[rl * 2 + (w & 1)] = m1;
                rid[rl * 2 + (w & 1)] = i1;
                rv2[rl * 2 + (w & 1)] = m2;
            }
        }
    }
    __syncthreads();

    if (tid < TM) {
        float a1 = rv1[tid * 2 + 0], b1 = rv1[tid * 2 + 1];
        int   ai = rid[tid * 2 + 0], bi = rid[tid * 2 + 1];
        float a2 = rv2[tid * 2 + 0], b2 = rv2[tid * 2 + 1];
        float m1, m2; int i1;
        if (b1 < a1 || (b1 == a1 && bi < ai)) { m1 = b1; i1 = bi; m2 = fminf(a1, b2); }
        else                                  { m1 = a1; i1 = ai; m2 = fminf(a2, b1); }
        size_t o = (size_t)(rbase + tid) * 8 + cbl;
        pval[o] = m1; pidx[o] = i1; pval2[o] = m2;
    }
}

// ---------------- merge 8 partials -> final idx; full-coverage flags ----------------
__global__ void merge_kernel(const float* __restrict__ pval, const int* __restrict__ pidx,
                             const float* __restrict__ pval2,
                             int* __restrict__ fidx, int* __restrict__ flags) {
    int row = blockIdx.x * blockDim.x + threadIdx.x;
    size_t o = (size_t)row * 8;
    float m1 = pval[o]; int i1 = pidx[o]; float m2 = pval2[o];
    #pragma unroll
    for (int c = 1; c < 8; ++c) {
        float b1 = pval[o + c]; int bi = pidx[o + c]; float b2 = pval2[o + c];
        if (b1 < m1 || (b1 == m1 && bi < i1)) { m2 = fminf(m1, b2); m1 = b1; i1 = bi; }
        else m2 = fminf(m2, b1);
    }
    fidx[row] = i1 & (K_CODES - 1);
    flags[row] = (!(m2 - m1 >= TAU)) ? 1 : 0;   // NaN-safe: flag unless provably safe
}

// ---------------- deterministic compaction (single wave, ballot prefix) ----------------
__global__ void compact_kernel(const int* __restrict__ flags,
                               int* __restrict__ list, int* __restrict__ count) {
    int lane = threadIdx.x;     // 64 threads, 1 block
    int base = 0;
    for (int it = 0; it < N_ROWS / 64; ++it) {
        int row = it * 64 + lane;
        int f = flags[row];
        unsigned long long m = __ballot(f != 0);
        if (f) {
            int pos = base + __popcll(m & ((1ull << lane) - 1ull));
            if (pos < CAP) list[pos] = row;
        }
        base += (int)__popcll(m);
    }
    if (lane == 0) *count = base > CAP ? CAP : base;
}

// ---------------- exact fp32 re-check: coalesced via transposed codebook ----------------
__global__ __launch_bounds__(256) void cleanup_kernel(
    const float* __restrict__ z, const float* __restrict__ cbkT,
    const float* __restrict__ norms,
    const int* __restrict__ count_p, const int* __restrict__ list,
    int* __restrict__ fidx)
{
    int count = *count_p;
    if (count < 0) count = 0; if (count > CAP) count = CAP;
    int base = blockIdx.x * RPB;
    if (base >= count) return;
    int nr = count - base; if (nr > RPB) nr = RPB;

    __shared__ float zs[RPB][256];
    __shared__ float sv[RPB][256];
    __shared__ int   si[RPB][256];
    __shared__ int   rows[RPB];
    const int tid = threadIdx.x;

    if (tid < RPB) rows[tid] = list[base + (tid < nr ? tid : 0)] & (N_ROWS - 1);
    __syncthreads();
    #pragma unroll
    for (int r = 0; r < RPB; ++r)
        zs[r][tid] = (r < nr) ? z[(size_t)rows[r] * D_DIM + tid] : 0.f;
    __syncthreads();

    // thread owns codes 4*tid..4*tid+3; fully coalesced float4 from cbkT[d][*]
    f32x4 acc[RPB];
    #pragma unroll
    for (int r = 0; r < RPB; ++r) acc[r] = (f32x4){0.f, 0.f, 0.f, 0.f};

    for (int d4 = 0; d4 < D_DIM / 4; ++d4) {
        float4 zv[RPB];
        #pragma unroll
        for (int r = 0; r < RPB; ++r) zv[r] = *(const float4*)&zs[r][d4 * 4];
        #pragma unroll
        for (int t = 0; t < 4; ++t) {
            int d = d4 * 4 + t;
            float4 c = *(const float4*)(cbkT + (size_t)d * K_CODES + tid * 4);
            #pragma unroll
            for (int r = 0; r < RPB; ++r) {
                float zd = ((const float*)&zv[r])[t];
                acc[r].x += zd * c.x; acc[r].y += zd * c.y;
                acc[r].z += zd * c.z; acc[r].w += zd * c.w;
            }
        }
    }

    float4 nv = *(const float4*)(norms + tid * 4);
    #pragma unroll
    for (int r = 0; r < RPB; ++r) {
        float d0 = nv.x - 2.f * acc[r].x;
        float d1 = nv.y - 2.f * acc[r].y;
        float d2 = nv.z - 2.f * acc[r].z;
        float d3 = nv.w - 2.f * acc[r].w;
        float best = d0; int bi = 4 * tid;
        if (d1 < best) { best = d1; bi = 4 * tid + 1; }
        if (d2 < best) { best = d2; bi = 4 * tid + 2; }
        if (d3 < best) { best = d3; bi = 4 * tid + 3; }
        sv[r][tid] = best; si[r][tid] = bi;
    }
    __syncthreads();
    for (int s = 128; s; s >>= 1) {
        if (tid < s) {
            #pragma unroll
            for (int r = 0; r < RPB; ++r) {
                float ov = sv[r][tid + s]; int oi = si[r][tid + s];
                if (ov < sv[r][tid] || (ov == sv[r][tid] && oi < si[r][tid])) {
                    sv[r][tid] = ov; si[r][tid] = oi;
                }
            }
        }
        __syncthreads();
    }
    if (tid < nr) fidx[rows[tid]] = si[tid][0] & (K_CODES - 1);
}

// ---------------- epilogue: all-aligned stores, clamped gather ----------------
__global__ void epilogue_kernel(const float* __restrict__ z, const float* __restrict__ cbk,
                                const int* __restrict__ fidx,
                                float* __restrict__ out, float* __restrict__ partials) {
    __shared__ float wsum[4];
    const int gtid = blockIdx.x * blockDim.x + threadIdx.x;
    const int stride = gridDim.x * blockDim.x;
    float lsum = 0.f;

    const int n4 = M_ELEMS / 4;
    for (int i4 = gtid; i4 < n4; i4 += stride) {
        float4 ze = *(const float4*)(z + (size_t)i4 * 4);
        int row = i4 >> 6;
        int d   = (i4 & 63) * 4;
        int code = fidx[row] & (K_CODES - 1);
        float4 zq = *(const float4*)(cbk + (size_t)code * D_DIM + d);
        *(float4*)(out + (size_t)i4 * 4) = ze;
        float dx = zq.x - ze.x, dy = zq.y - ze.y, dz = zq.z - ze.z, dw = zq.w - ze.w;
        lsum += dx * dx + dy * dy + dz * dz + dw * dw;
    }

    float* out2 = out + M_ELEMS + 1;
    const int g2 = (M_ELEMS - 4) / 4;
    for (int g = gtid; g < g2; g += stride) {
        int i0 = 3 + 4 * g;
        int row = i0 >> 8;
        int d0  = i0 & 255;
        int code = fidx[row] & (K_CODES - 1);
        float4 v;
        if (d0 <= D_DIM - 4) {
            f4u t = *(const f4u*)(cbk + (size_t)code * D_DIM + d0);
            v = (float4){t.x, t.y, t.z, t.w};
        } else {
            #pragma unroll
            for (int t = 0; t < 4; ++t) {
                int i = i0 + t;
                int c2 = fidx[i >> 8] & (K_CODES - 1);
                ((float*)&v)[t] = cbk[(size_t)c2 * D_DIM + (i & 255)];
            }
        }
        *(float4*)(out2 + i0) = v;        // addr = out + M + 4 + 4g : 16B aligned
    }
    if (gtid == 0) {
        int c0 = fidx[0] & (K_CODES - 1);
        int cl = fidx[N_ROWS - 1] & (K_CODES - 1);
        out2[0] = cbk[(size_t)c0 * D_DIM + 0];
        out2[1] = cbk[(size_t)c0 * D_DIM + 1];
        out2[2] = cbk[(size_t)c0 * D_DIM + 2];
        out2[M_ELEMS - 1] = cbk[(size_t)cl * D_DIM + 255];
    }

    #pragma unroll
    for (int off = 32; off; off >>= 1) lsum += __shfl_down(lsum, off);
    if ((threadIdx.x & 63) == 0) wsum[threadIdx.x >> 6] = lsum;
    __syncthreads();
    if (threadIdx.x == 0)
        partials[blockIdx.x] = wsum[0] + wsum[1] + wsum[2] + wsum[3];
}

__global__ void finalize_kernel(const float* __restrict__ partials, float* __restrict__ out) {
    __shared__ float wsum[4];
    float s = 0.f;
    for (int i = threadIdx.x; i < 2048; i += 256) s += partials[i];
    #pragma unroll
    for (int off = 32; off; off >>= 1) s += __shfl_down(s, off);
    if ((threadIdx.x & 63) == 0) wsum[threadIdx.x >> 6] = s;
    __syncthreads();
    if (threadIdx.x == 0)
        out[M_ELEMS] = 2.0f * (wsum[0] + wsum[1] + wsum[2] + wsum[3]) / (float)M_ELEMS;
}

extern "C" void kernel_launch(void* const* d_in, const int* in_sizes, int n_in,
                              void* d_out, int out_size, void* d_ws, size_t ws_size,
                              hipStream_t stream) {
    const float* z   = (const float*)d_in[0];
    const float* cbk = (const float*)d_in[1];
    float* out = (float*)d_out;

    char* ws = (char*)d_ws;
    _Float16* zh  = (_Float16*)ws;                                   // 16.8 MB
    _Float16* eh  = zh + (size_t)M_ELEMS;                            // 512 KB
    float* cbkT   = (float*)(eh + (size_t)K_CODES * D_DIM);          // 1 MB
    float* norms  = cbkT + (size_t)K_CODES * D_DIM;                  // 4 KB
    float* pval   = norms + K_CODES;                                 // 1 MB
    float* pval2  = pval + (size_t)N_ROWS * 8;                       // 1 MB
    int*   pidx   = (int*)(pval2 + (size_t)N_ROWS * 8);              // 1 MB
    int*   fidx   = pidx + (size_t)N_ROWS * 8;                       // 128 KB
    int*   flags  = fidx + N_ROWS;                                   // 128 KB
    int*   count  = flags + N_ROWS;                                  // 64 B
    int*   list   = count + 16;                                      // 32 KB
    float* partials = (float*)(list + CAP);                          // 8 KB

    norms_kernel<<<K_CODES / 4, 256, 0, stream>>>(cbk, norms);
    convert_f16_kernel<<<1024, 256, 0, stream>>>(z, zh, M_ELEMS / 4);
    prep_codebook_kernel<<<256, 256, 0, stream>>>(cbk, cbkT, eh);
    vq_main_f16<<<(N_ROWS / TM) * (K_CODES / TN), 256, 0, stream>>>(
        zh, eh, norms, pval, pidx, pval2);
    merge_kernel<<<N_ROWS / 256, 256, 0, stream>>>(pval, pidx, pval2, fidx, flags);
    compact_kernel<<<1, 64, 0, stream>>>(flags, list, count);
    cleanup_kernel<<<CAP / RPB, 256, 0, stream>>>(z, cbkT, norms, count, list, fidx);
    epilogue_kernel<<<2048, 256, 0, stream>>>(z, cbk, fidx, out, partials);
    finalize_kernel<<<1, 256, 0, stream>>>(partials, out);
}

// Round 6
// 218.084 us; speedup vs baseline: 1.6133x; 1.6133x over previous
//
#include <hip/hip_runtime.h>

// VQ-VAE quantization, round 6: round-5 pipeline with parallel deterministic
// compaction (the 144us serial single-wave scan was 40% of runtime).
// N=32768 rows (D=256), K=1024 codes.
// dist = ||e_k||^2 - 2 z.e_k  (||z||^2 dropped: argmin-invariant)
// Approx dot = f16(z).f16(e) in fp32 accum; rows with top-2 gap < TAU
// get exact fp32 re-check against the whole codebook.

#define N_ROWS 32768
#define K_CODES 1024
#define D_DIM 256
#define M_ELEMS 8388608   // N_ROWS * D_DIM

#define TM 128
#define TN 128
#define BK 64
#define TAU 0.25f
#define CAP 8192
#define RPB 8             // cleanup rows per block

typedef __attribute__((ext_vector_type(8))) _Float16 half8;
typedef __attribute__((ext_vector_type(4))) _Float16 half4;
typedef __attribute__((ext_vector_type(4))) float f32x4;
typedef __attribute__((ext_vector_type(4), aligned(4))) float f4u;

__device__ inline void async16(const void* g, void* l) {
    __builtin_amdgcn_global_load_lds(
        (const __attribute__((address_space(1))) unsigned int*)g,
        (__attribute__((address_space(3))) unsigned int*)l, 16, 0, 0);
}

// ---------------- fp32 -> f16 (RN) ----------------
__global__ void convert_f16_kernel(const float* __restrict__ src,
                                   _Float16* __restrict__ dst, int n4) {
    int stride = gridDim.x * blockDim.x;
    for (int i = blockIdx.x * blockDim.x + threadIdx.x; i < n4; i += stride) {
        float4 v = *(const float4*)(src + (size_t)i * 4);
        half4 h = {(_Float16)v.x, (_Float16)v.y, (_Float16)v.z, (_Float16)v.w};
        *(half4*)(dst + (size_t)i * 4) = h;
    }
}

// ---------------- codebook prep: f16 copy + fp32 transpose (1D grid) ----------------
__global__ void prep_codebook_kernel(const float* __restrict__ cbk,
                                     float* __restrict__ cbkT,
                                     _Float16* __restrict__ eh) {
    __shared__ float tile[32][33];
    int b  = blockIdx.x;              // 0..255
    int bk = b & 31;                  // code block
    int bd = b >> 5;                  // dim block (0..7)
    int r  = threadIdx.x >> 3;        // 0..31
    int c4 = (threadIdx.x & 7) * 4;   // 0,4,..,28
    int k = bk * 32 + r;
    int d = bd * 32 + c4;
    float4 v = *(const float4*)(cbk + (size_t)k * D_DIM + d);
    half4 h = {(_Float16)v.x, (_Float16)v.y, (_Float16)v.z, (_Float16)v.w};
    *(half4*)(eh + (size_t)k * D_DIM + d) = h;
    tile[r][c4 + 0] = v.x; tile[r][c4 + 1] = v.y;
    tile[r][c4 + 2] = v.z; tile[r][c4 + 3] = v.w;
    __syncthreads();
    float4 o = {tile[c4 + 0][r], tile[c4 + 1][r], tile[c4 + 2][r], tile[c4 + 3][r]};
    *(float4*)(cbkT + (size_t)(bd * 32 + r) * K_CODES + bk * 32 + c4) = o;
}

// ---------------- codebook norms (exact fp32) ----------------
__global__ void norms_kernel(const float* __restrict__ cbk, float* __restrict__ norms) {
    int wave = threadIdx.x >> 6;
    int lane = threadIdx.x & 63;
    int code = blockIdx.x * 4 + wave;       // grid = K/4 = 256
    const float4 v = *(const float4*)(cbk + (size_t)code * D_DIM + lane * 4);
    float s = v.x * v.x + v.y * v.y + v.z * v.z + v.w * v.w;
    #pragma unroll
    for (int off = 32; off; off >>= 1) s += __shfl_down(s, off);
    if (lane == 0) norms[code] = s;
}

// ---------------- main: f16 MFMA, global_load_lds, XOR-swizzled LDS ----------------
__global__ __launch_bounds__(256, 2) void vq_main_f16(
    const _Float16* __restrict__ zh, const _Float16* __restrict__ eh,
    const float* __restrict__ norms,
    float* __restrict__ pval, int* __restrict__ pidx, float* __restrict__ pval2)
{
    __shared__ __align__(16) _Float16 Ah[TM * BK];
    __shared__ __align__(16) _Float16 Bh[TN * BK];

    const int tid  = threadIdx.x;
    const int bid  = blockIdx.x;            // grid = 256 * 8 = 2048
    const int cbl  = bid & 7;
    const int rb   = bid >> 3;
    const int rbase = rb * TM;
    const int cbase = cbl * TN;

    const int w    = tid >> 6;
    const int lane = tid & 63;
    const int quad = lane >> 4;
    const int ml   = lane & 15;
    const int wrow = (w >> 1) * 64;
    const int wcol = (w & 1) * 64;

    f32x4 acc[4][4];
    #pragma unroll
    for (int i = 0; i < 4; ++i)
        #pragma unroll
        for (int j = 0; j < 4; ++j)
            acc[i][j] = (f32x4){0.f, 0.f, 0.f, 0.f};

    for (int dc = 0; dc < D_DIM / BK; ++dc) {   // 4 iterations
        // LDS slot (row,seg) holds global k-chunk seg^(row&7): XOR swizzle on
        // the SOURCE address (global_load_lds dest must stay lane-linear).
        #pragma unroll
        for (int q = 0; q < 4; ++q) {
            int cc  = q * 256 + tid;        // 0..1023
            int row = cc >> 3;
            int seg = cc & 7;
            int sg  = seg ^ (row & 7);
            async16(zh + (size_t)(rbase + row) * D_DIM + dc * BK + sg * 8, &Ah[cc * 8]);
            async16(eh + (size_t)(cbase + row) * D_DIM + dc * BK + sg * 8, &Bh[cc * 8]);
        }
        __syncthreads();

        half8 a[4][2];
        #pragma unroll
        for (int i = 0; i < 4; ++i) {
            int r = wrow + i * 16 + ml;
            #pragma unroll
            for (int kc = 0; kc < 2; ++kc)
                a[i][kc] = *(const half8*)&Ah[r * BK + (((kc << 2) + quad) ^ (r & 7)) * 8];
        }
        #pragma unroll
        for (int j = 0; j < 4; ++j) {
            int c = wcol + j * 16 + ml;
            #pragma unroll
            for (int kc = 0; kc < 2; ++kc) {
                half8 b = *(const half8*)&Bh[c * BK + (((kc << 2) + quad) ^ (c & 7)) * 8];
                #pragma unroll
                for (int i = 0; i < 4; ++i)
                    acc[i][j] = __builtin_amdgcn_mfma_f32_16x16x32_f16(a[i][kc], b, acc[i][j], 0, 0, 0);
            }
        }
        __syncthreads();
    }

    // ------- per-row top-2 over this block's 128 codes -------
    float nrm[4];
    int   codej[4];
    #pragma unroll
    for (int j = 0; j < 4; ++j) {
        codej[j] = cbase + wcol + j * 16 + ml;
        nrm[j]   = norms[codej[j]];
    }

    float* rv1 = (float*)Ah;   // [128][2] overlays (loop ended on syncthreads)
    int*   rid = (int*)&Ah[TM * BK / 2];
    float* rv2 = (float*)Bh;

    #pragma unroll
    for (int i = 0; i < 4; ++i) {
        #pragma unroll
        for (int r = 0; r < 4; ++r) {
            float m1 = 3.4e38f, m2 = 3.4e38f;
            int   i1 = cbase;    // safe default (valid code) even if all dists NaN
            #pragma unroll
            for (int j = 0; j < 4; ++j) {
                float dist = nrm[j] - 2.f * acc[i][j][r];
                int code = codej[j];
                if (dist < m1 || (dist == m1 && code < i1)) { m2 = m1; m1 = dist; i1 = code; }
                else m2 = fminf(m2, dist);
            }
            #pragma unroll
            for (int off = 1; off < 16; off <<= 1) {
                float om1 = __shfl_xor(m1, off);
                int   oi1 = __shfl_xor(i1, off);
                float om2 = __shfl_xor(m2, off);
                if (om1 < m1 || (om1 == m1 && oi1 < i1)) { m2 = fminf(m1, om2); m1 = om1; i1 = oi1; }
                else m2 = fminf(m2, om1);
            }
            if (ml == 0) {
                int rl = wrow + i * 16 + quad * 4 + r;
                rv1[rl * 2 + (w & 1)] = m1;
                rid[rl * 2 + (w & 1)] = i1;
                rv2[rl * 2 + (w & 1)] = m2;
            }
        }
    }
    __syncthreads();

    if (tid < TM) {
        float a1 = rv1[tid * 2 + 0], b1 = rv1[tid * 2 + 1];
        int   ai = rid[tid * 2 + 0], bi = rid[tid * 2 + 1];
        float a2 = rv2[tid * 2 + 0], b2 = rv2[tid * 2 + 1];
        float m1, m2; int i1;
        if (b1 < a1 || (b1 == a1 && bi < ai)) { m1 = b1; i1 = bi; m2 = fminf(a1, b2); }
        else                                  { m1 = a1; i1 = ai; m2 = fminf(a2, b1); }
        size_t o = (size_t)(rbase + tid) * 8 + cbl;
        pval[o] = m1; pidx[o] = i1; pval2[o] = m2;
    }
}

// ---------------- merge 8 partials -> final idx; full-coverage flags ----------------
__global__ void merge_kernel(const float* __restrict__ pval, const int* __restrict__ pidx,
                             const float* __restrict__ pval2,
                             int* __restrict__ fidx, int* __restrict__ flags) {
    int row = blockIdx.x * blockDim.x + threadIdx.x;
    size_t o = (size_t)row * 8;
    float m1 = pval[o]; int i1 = pidx[o]; float m2 = pval2[o];
    #pragma unroll
    for (int c = 1; c < 8; ++c) {
        float b1 = pval[o + c]; int bi = pidx[o + c]; float b2 = pval2[o + c];
        if (b1 < m1 || (b1 == m1 && bi < i1)) { m2 = fminf(m1, b2); m1 = b1; i1 = bi; }
        else m2 = fminf(m2, b1);
    }
    fidx[row] = i1 & (K_CODES - 1);
    flags[row] = (!(m2 - m1 >= TAU)) ? 1 : 0;   // NaN-safe: flag unless provably safe
}

// ---------------- parallel deterministic compaction (1 block, 1024 threads) ----------------
// Each thread owns 32 contiguous rows; block-wide inclusive scan in LDS gives
// deterministic global-row-order positions. Replaces the 144us serial wave.
__global__ __launch_bounds__(1024) void compact_kernel(
    const int* __restrict__ flags, int* __restrict__ list, int* __restrict__ count)
{
    __shared__ int offs[1024];
    const int t = threadIdx.x;
    const int RPT = N_ROWS / 1024;   // 32
    const int base_row = t * RPT;

    int f[RPT];
    int cnt = 0;
    #pragma unroll
    for (int i = 0; i < RPT; i += 4) {
        int4 v = *(const int4*)(flags + base_row + i);
        f[i + 0] = v.x; f[i + 1] = v.y; f[i + 2] = v.z; f[i + 3] = v.w;
        cnt += v.x + v.y + v.z + v.w;
    }
    offs[t] = cnt;
    __syncthreads();
    for (int d = 1; d < 1024; d <<= 1) {
        int add = (t >= d) ? offs[t - d] : 0;
        __syncthreads();
        offs[t] += add;
        __syncthreads();
    }
    int pos = offs[t] - cnt;   // exclusive prefix
    #pragma unroll
    for (int i = 0; i < RPT; ++i) {
        if (f[i]) { if (pos < CAP) list[pos] = base_row + i; pos++; }
    }
    if (t == 1023) {
        int total = offs[1023];
        *count = total > CAP ? CAP : total;
    }
}

// ---------------- exact fp32 re-check: coalesced via transposed codebook ----------------
__global__ __launch_bounds__(256) void cleanup_kernel(
    const float* __restrict__ z, const float* __restrict__ cbkT,
    const float* __restrict__ norms,
    const int* __restrict__ count_p, const int* __restrict__ list,
    int* __restrict__ fidx)
{
    int count = *count_p;
    if (count < 0) count = 0; if (count > CAP) count = CAP;
    int base = blockIdx.x * RPB;
    if (base >= count) return;
    int nr = count - base; if (nr > RPB) nr = RPB;

    __shared__ float zs[RPB][256];
    __shared__ float sv[RPB][256];
    __shared__ int   si[RPB][256];
    __shared__ int   rows[RPB];
    const int tid = threadIdx.x;

    if (tid < RPB) rows[tid] = list[base + (tid < nr ? tid : 0)] & (N_ROWS - 1);
    __syncthreads();
    #pragma unroll
    for (int r = 0; r < RPB; ++r)
        zs[r][tid] = (r < nr) ? z[(size_t)rows[r] * D_DIM + tid] : 0.f;
    __syncthreads();

    // thread owns codes 4*tid..4*tid+3; fully coalesced float4 from cbkT[d][*]
    f32x4 acc[RPB];
    #pragma unroll
    for (int r = 0; r < RPB; ++r) acc[r] = (f32x4){0.f, 0.f, 0.f, 0.f};

    for (int d4 = 0; d4 < D_DIM / 4; ++d4) {
        float4 zv[RPB];
        #pragma unroll
        for (int r = 0; r < RPB; ++r) zv[r] = *(const float4*)&zs[r][d4 * 4];
        #pragma unroll
        for (int t = 0; t < 4; ++t) {
            int d = d4 * 4 + t;
            float4 c = *(const float4*)(cbkT + (size_t)d * K_CODES + tid * 4);
            #pragma unroll
            for (int r = 0; r < RPB; ++r) {
                float zd = ((const float*)&zv[r])[t];
                acc[r].x += zd * c.x; acc[r].y += zd * c.y;
                acc[r].z += zd * c.z; acc[r].w += zd * c.w;
            }
        }
    }

    float4 nv = *(const float4*)(norms + tid * 4);
    #pragma unroll
    for (int r = 0; r < RPB; ++r) {
        float d0 = nv.x - 2.f * acc[r].x;
        float d1 = nv.y - 2.f * acc[r].y;
        float d2 = nv.z - 2.f * acc[r].z;
        float d3 = nv.w - 2.f * acc[r].w;
        float best = d0; int bi = 4 * tid;
        if (d1 < best) { best = d1; bi = 4 * tid + 1; }
        if (d2 < best) { best = d2; bi = 4 * tid + 2; }
        if (d3 < best) { best = d3; bi = 4 * tid + 3; }
        sv[r][tid] = best; si[r][tid] = bi;
    }
    __syncthreads();
    for (int s = 128; s; s >>= 1) {
        if (tid < s) {
            #pragma unroll
            for (int r = 0; r < RPB; ++r) {
                float ov = sv[r][tid + s]; int oi = si[r][tid + s];
                if (ov < sv[r][tid] || (ov == sv[r][tid] && oi < si[r][tid])) {
                    sv[r][tid] = ov; si[r][tid] = oi;
                }
            }
        }
        __syncthreads();
    }
    if (tid < nr) fidx[rows[tid]] = si[tid][0] & (K_CODES - 1);
}

// ---------------- epilogue: all-aligned stores, clamped gather ----------------
__global__ void epilogue_kernel(const float* __restrict__ z, const float* __restrict__ cbk,
                                const int* __restrict__ fidx,
                                float* __restrict__ out, float* __restrict__ partials) {
    __shared__ float wsum[4];
    const int gtid = blockIdx.x * blockDim.x + threadIdx.x;
    const int stride = gridDim.x * blockDim.x;
    float lsum = 0.f;

    const int n4 = M_ELEMS / 4;
    for (int i4 = gtid; i4 < n4; i4 += stride) {
        float4 ze = *(const float4*)(z + (size_t)i4 * 4);
        int row = i4 >> 6;
        int d   = (i4 & 63) * 4;
        int code = fidx[row] & (K_CODES - 1);
        float4 zq = *(const float4*)(cbk + (size_t)code * D_DIM + d);
        *(float4*)(out + (size_t)i4 * 4) = ze;
        float dx = zq.x - ze.x, dy = zq.y - ze.y, dz = zq.z - ze.z, dw = zq.w - ze.w;
        lsum += dx * dx + dy * dy + dz * dz + dw * dw;
    }

    float* out2 = out + M_ELEMS + 1;
    const int g2 = (M_ELEMS - 4) / 4;
    for (int g = gtid; g < g2; g += stride) {
        int i0 = 3 + 4 * g;
        int row = i0 >> 8;
        int d0  = i0 & 255;
        int code = fidx[row] & (K_CODES - 1);
        float4 v;
        if (d0 <= D_DIM - 4) {
            f4u t = *(const f4u*)(cbk + (size_t)code * D_DIM + d0);
            v = (float4){t.x, t.y, t.z, t.w};
        } else {
            #pragma unroll
            for (int t = 0; t < 4; ++t) {
                int i = i0 + t;
                int c2 = fidx[i >> 8] & (K_CODES - 1);
                ((float*)&v)[t] = cbk[(size_t)c2 * D_DIM + (i & 255)];
            }
        }
        *(float4*)(out2 + i0) = v;        // addr = out + M + 4 + 4g : 16B aligned
    }
    if (gtid == 0) {
        int c0 = fidx[0] & (K_CODES - 1);
        int cl = fidx[N_ROWS - 1] & (K_CODES - 1);
        out2[0] = cbk[(size_t)c0 * D_DIM + 0];
        out2[1] = cbk[(size_t)c0 * D_DIM + 1];
        out2[2] = cbk[(size_t)c0 * D_DIM + 2];
        out2[M_ELEMS - 1] = cbk[(size_t)cl * D_DIM + 255];
    }

    #pragma unroll
    for (int off = 32; off; off >>= 1) lsum += __shfl_down(lsum, off);
    if ((threadIdx.x & 63) == 0) wsum[threadIdx.x >> 6] = lsum;
    __syncthreads();
    if (threadIdx.x == 0)
        partials[blockIdx.x] = wsum[0] + wsum[1] + wsum[2] + wsum[3];
}

__global__ void finalize_kernel(const float* __restrict__ partials, float* __restrict__ out) {
    __shared__ float wsum[4];
    float s = 0.f;
    for (int i = threadIdx.x; i < 2048; i += 256) s += partials[i];
    #pragma unroll
    for (int off = 32; off; off >>= 1) s += __shfl_down(s, off);
    if ((threadIdx.x & 63) == 0) wsum[threadIdx.x >> 6] = s;
    __syncthreads();
    if (threadIdx.x == 0)
        out[M_ELEMS] = 2.0f * (wsum[0] + wsum[1] + wsum[2] + wsum[3]) / (float)M_ELEMS;
}

extern "C" void kernel_launch(void* const* d_in, const int* in_sizes, int n_in,
                              void* d_out, int out_size, void* d_ws, size_t ws_size,
                              hipStream_t stream) {
    const float* z   = (const float*)d_in[0];
    const float* cbk = (const float*)d_in[1];
    float* out = (float*)d_out;

    char* ws = (char*)d_ws;
    _Float16* zh  = (_Float16*)ws;                                   // 16.8 MB
    _Float16* eh  = zh + (size_t)M_ELEMS;                            // 512 KB
    float* cbkT   = (float*)(eh + (size_t)K_CODES * D_DIM);          // 1 MB
    float* norms  = cbkT + (size_t)K_CODES * D_DIM;                  // 4 KB
    float* pval   = norms + K_CODES;                                 // 1 MB
    float* pval2  = pval + (size_t)N_ROWS * 8;                       // 1 MB
    int*   pidx   = (int*)(pval2 + (size_t)N_ROWS * 8);              // 1 MB
    int*   fidx   = pidx + (size_t)N_ROWS * 8;                       // 128 KB
    int*   flags  = fidx + N_ROWS;                                   // 128 KB
    int*   count  = flags + N_ROWS;                                  // 64 B
    int*   list   = count + 16;                                      // 32 KB
    float* partials = (float*)(list + CAP);                          // 8 KB

    norms_kernel<<<K_CODES / 4, 256, 0, stream>>>(cbk, norms);
    convert_f16_kernel<<<1024, 256, 0, stream>>>(z, zh, M_ELEMS / 4);
    prep_codebook_kernel<<<256, 256, 0, stream>>>(cbk, cbkT, eh);
    vq_main_f16<<<(N_ROWS / TM) * (K_CODES / TN), 256, 0, stream>>>(
        zh, eh, norms, pval, pidx, pval2);
    merge_kernel<<<N_ROWS / 256, 256, 0, stream>>>(pval, pidx, pval2, fidx, flags);
    compact_kernel<<<1, 1024, 0, stream>>>(flags, list, count);
    cleanup_kernel<<<CAP / RPB, 256, 0, stream>>>(z, cbkT, norms, count, list, fidx);
    epilogue_kernel<<<2048, 256, 0, stream>>>(z, cbk, fidx, out, partials);
    finalize_kernel<<<1, 256, 0, stream>>>(partials, out);
}